// Round 4
// baseline (81.571 us; speedup 1.0000x reference)
//
#include <hip/hip_runtime.h>
#include <math.h>

#define DD 1024
#define TT 4096
#define BB 16
#define KK 4
#define CC 1000
#define TEMP_F 0.07f
#define EPS_F 1e-6f
#define NPROJ 2048

// ---------- sorted-8 register-list helpers (all static indexing) ----------
#define CE(a, b) { float _mx = fmaxf(a, b), _mn = fminf(a, b); a = _mx; b = _mn; }
#define INS8(y_) { float y = (y_); \
    CE(s0, y) CE(s1, y) CE(s2, y) CE(s3, y) CE(s4, y) CE(s5, y) CE(s6, y) CE(s7, y) }
#define RESORT8() { \
    CE(s0, s4) CE(s1, s5) CE(s2, s6) CE(s3, s7) \
    CE(s0, s2) CE(s1, s3) CE(s4, s6) CE(s5, s7) \
    CE(s0, s1) CE(s2, s3) CE(s4, s5) CE(s6, s7) }
#define WMERGE(off) { \
    float t0 = __shfl_xor(s0, off), t1 = __shfl_xor(s1, off), \
          t2 = __shfl_xor(s2, off), t3 = __shfl_xor(s3, off), \
          t4 = __shfl_xor(s4, off), t5 = __shfl_xor(s5, off), \
          t6 = __shfl_xor(s6, off), t7 = __shfl_xor(s7, off); \
    s0 = fmaxf(s0, t7); s1 = fmaxf(s1, t6); s2 = fmaxf(s2, t5); s3 = fmaxf(s3, t4); \
    s4 = fmaxf(s4, t3); s5 = fmaxf(s5, t2); s6 = fmaxf(s6, t1); s7 = fmaxf(s7, t0); \
    RESORT8() }

__device__ __forceinline__ float4 sigw4(const float* __restrict__ v,
                                        const float* __restrict__ m, int off) {
    float4 vv = *reinterpret_cast<const float4*>(v + off);
    float4 mm = *reinterpret_cast<const float4*>(m + off);
    float4 r;
    r.x = vv.x * (1.f / (1.f + expf(-mm.x)));
    r.y = vv.y * (1.f / (1.f + expf(-mm.y)));
    r.z = vv.z * (1.f / (1.f + expf(-mm.z)));
    r.w = vv.w * (1.f / (1.f + expf(-mm.w)));
    return r;
}

// Kernel 1: raw (unnormalized) projections. s_k = v_k*sigmoid(m_k) is computed
// per-lane in registers: elementwise, no syncs, no LDS, no serial u stage.
//   blocks [0,NPROJ):        r[b,t,k]  = E[b,t,:] . s_k
//   blocks [NPROJ,NPROJ+CC): wraw[k,c] = cls_W[k,c,:] . s_k
__global__ __launch_bounds__(256) void k_main(const float* __restrict__ E,
                                              const float* __restrict__ W,
                                              const float* __restrict__ v,
                                              const float* __restrict__ m,
                                              float* __restrict__ c0,
                                              float* __restrict__ wraw) {
    int tid = threadIdx.x, w = tid >> 6, lane = tid & 63;
    if (blockIdx.x < NPROJ) {
        float4 S[KK][4];
#pragma unroll
        for (int k = 0; k < KK; ++k)
#pragma unroll
            for (int j = 0; j < 4; ++j)
                S[k][j] = sigw4(v, m, k * DD + lane * 4 + j * 256);
        const int ITERS = (BB * TT) / (NPROJ * 4);  // 8
#pragma unroll 1
        for (int it = 0; it < ITERS; ++it) {
            size_t g = (size_t)(blockIdx.x * 4 + w) + (size_t)it * (NPROJ * 4);
            const float* e = E + g * DD;
            float a0 = 0.f, a1 = 0.f, a2 = 0.f, a3 = 0.f;
#pragma unroll
            for (int j = 0; j < 4; ++j) {
                float4 ev = *reinterpret_cast<const float4*>(e + lane * 4 + j * 256);
                a0 += ev.x * S[0][j].x + ev.y * S[0][j].y + ev.z * S[0][j].z + ev.w * S[0][j].w;
                a1 += ev.x * S[1][j].x + ev.y * S[1][j].y + ev.z * S[1][j].z + ev.w * S[1][j].w;
                a2 += ev.x * S[2][j].x + ev.y * S[2][j].y + ev.z * S[2][j].z + ev.w * S[2][j].w;
                a3 += ev.x * S[3][j].x + ev.y * S[3][j].y + ev.z * S[3][j].z + ev.w * S[3][j].w;
            }
#pragma unroll
            for (int off = 32; off; off >>= 1) {
                a0 += __shfl_xor(a0, off);
                a1 += __shfl_xor(a1, off);
                a2 += __shfl_xor(a2, off);
                a3 += __shfl_xor(a3, off);
            }
            if (lane == 0)
                *reinterpret_cast<float4*>(c0 + g * 4) = make_float4(a0, a1, a2, a3);
        }
    } else {
        int c = blockIdx.x - NPROJ;  // wave w handles k=w
        float4 S4[4];
#pragma unroll
        for (int j = 0; j < 4; ++j)
            S4[j] = sigw4(v, m, w * DD + lane * 4 + j * 256);
        const float* wr = W + ((size_t)w * CC + c) * DD;
        float acc = 0.f;
#pragma unroll
        for (int j = 0; j < 4; ++j) {
            float4 wv = *reinterpret_cast<const float4*>(wr + lane * 4 + j * 256);
            acc += wv.x * S4[j].x + wv.y * S4[j].y + wv.z * S4[j].z + wv.w * S4[j].w;
        }
#pragma unroll
        for (int off = 32; off; off >>= 1) acc += __shfl_xor(acc, off);
        if (lane == 0) wraw[w * CC + c] = acc;
    }
}

// Kernel 2: one block per b. Phase 1: norms ||s_k|| and grams s_j.s_k (10 short
// dots). Phase 2: wave w = k: scale raw coeffs, peel recurrence, softmax stats +
// single-pass top-8 -> csc[k]. Phase 3: out[b,:].
__global__ __launch_bounds__(256) void k_peel_out(const float* __restrict__ c0,
                                                  const float* __restrict__ wraw,
                                                  const float* __restrict__ v,
                                                  const float* __restrict__ m,
                                                  const float* __restrict__ beta,
                                                  const float* __restrict__ bias,
                                                  const float* __restrict__ alpha,
                                                  float* __restrict__ out) {
    __shared__ float red[10];  // ss0..ss3, d01,d02,d03,d12,d13,d23
    __shared__ float csc[KK];
    int tid = threadIdx.x, w = tid >> 6, lane = tid & 63;
    int b = blockIdx.x;
    static const int PJ[10] = {0, 1, 2, 3, 0, 0, 0, 1, 1, 2};
    static const int PK[10] = {0, 1, 2, 3, 1, 2, 3, 2, 3, 3};
#pragma unroll 1
    for (int p = w; p < 10; p += 4) {
        int j = PJ[p], k = PK[p];
        float acc = 0.f;
#pragma unroll
        for (int i = 0; i < 16; ++i) {
            int d = lane + i * 64;
            float sj = v[j * DD + d] * (1.f / (1.f + expf(-m[j * DD + d])));
            float sk = (j == k) ? sj
                                : v[k * DD + d] * (1.f / (1.f + expf(-m[k * DD + d])));
            acc += sj * sk;
        }
#pragma unroll
        for (int off = 32; off; off >>= 1) acc += __shfl_xor(acc, off);
        if (lane == 0) red[p] = acc;
    }
    __syncthreads();
    float inv0 = 1.f / (sqrtf(red[0]) + EPS_F);
    float inv1 = 1.f / (sqrtf(red[1]) + EPS_F);
    float inv2 = 1.f / (sqrtf(red[2]) + EPS_F);
    float inv3 = 1.f / (sqrtf(red[3]) + EPS_F);
    float g01 = red[4] * inv0 * inv1, g02 = red[5] * inv0 * inv2,
          g03 = red[6] * inv0 * inv3, g12 = red[7] * inv1 * inv2,
          g13 = red[8] * inv1 * inv3, g23 = red[9] * inv2 * inv3;
    float b0 = beta[0], b1 = beta[1], b2 = beta[2];

    float fk[64];
    float mx = -INFINITY;
#pragma unroll
    for (int i = 0; i < 64; ++i) {
        int t = lane + i * 64;
        float4 cv = *reinterpret_cast<const float4*>(c0 + ((size_t)b * TT + t) * 4);
        float f0 = cv.x * inv0;
        float f1 = cv.y * inv1 - b0 * g01 * f0;
        float f2 = cv.z * inv2 - b0 * g02 * f0 - b1 * g12 * f1;
        float f3 = cv.w * inv3 - b0 * g03 * f0 - b1 * g13 * f1 - b2 * g23 * f2;
        float f = (w == 0) ? f0 : ((w == 1) ? f1 : ((w == 2) ? f2 : f3));
        fk[i] = f; mx = fmaxf(mx, f);
    }
#pragma unroll
    for (int off = 32; off; off >>= 1) mx = fmaxf(mx, __shfl_xor(mx, off));
    const float invT = 1.f / TEMP_F;
    float se = 0.f, sce = 0.f;
#pragma unroll
    for (int i = 0; i < 64; ++i) {
        float e = expf((fk[i] - mx) * invT);
        se += e; sce += fk[i] * e;
    }
#pragma unroll
    for (int off = 32; off; off >>= 1) {
        se += __shfl_xor(se, off);
        sce += __shfl_xor(sce, off);
    }
    float zsoft = sce / se;
    float s0 = -INFINITY, s1 = -INFINITY, s2 = -INFINITY, s3 = -INFINITY,
          s4 = -INFINITY, s5 = -INFINITY, s6 = -INFINITY, s7 = -INFINITY;
#pragma unroll
    for (int i = 0; i < 64; ++i) INS8(fk[i]);
    WMERGE(1) WMERGE(2) WMERGE(4) WMERGE(8) WMERGE(16) WMERGE(32)
    if (lane == 0) {
        float sumtop = s0 + s1 + s2 + s3 + s4 + s5 + s6 + s7;
        csc[w] = 0.5f * (sumtop + zsoft);
    }
    __syncthreads();
    float al0 = alpha[0], al1 = alpha[1], al2 = alpha[2], al3 = alpha[3];
    // fold the wdot normalization into the per-k scalar
    float c0s = csc[0] * inv0, c1s = csc[1] * inv1,
          c2s = csc[2] * inv2, c3s = csc[3] * inv3;
    for (int c = tid; c < CC; c += 256) {
        float s = al0 * (c0s * wraw[0 * CC + c] + bias[0 * CC + c])
                + al1 * (c1s * wraw[1 * CC + c] + bias[1 * CC + c])
                + al2 * (c2s * wraw[2 * CC + c] + bias[2 * CC + c])
                + al3 * (c3s * wraw[3 * CC + c] + bias[3 * CC + c]);
        out[(size_t)b * CC + c] = s;
    }
}

extern "C" void kernel_launch(void* const* d_in, const int* in_sizes, int n_in,
                              void* d_out, int out_size, void* d_ws, size_t ws_size,
                              hipStream_t stream) {
    const float* E     = (const float*)d_in[0];
    const float* v     = (const float*)d_in[1];
    const float* m     = (const float*)d_in[2];
    const float* W     = (const float*)d_in[3];
    const float* cb    = (const float*)d_in[4];
    const float* beta  = (const float*)d_in[5];
    const float* alpha = (const float*)d_in[6];
    float* out = (float*)d_out;
    float* ws = (float*)d_ws;

    float* wraw = ws;          // K*C = 4000 floats (pad to 4096)
    float* c0   = ws + 4096;   // B*T*K = 262144 floats, 16B-aligned

    k_main<<<NPROJ + CC, 256, 0, stream>>>(E, W, v, m, c0, wraw);
    k_peel_out<<<BB, 256, 0, stream>>>(c0, wraw, v, m, beta, cb, alpha, out);
}

// Round 5
// 63.088 us; speedup vs baseline: 1.2930x; 1.2930x over previous
//
#include <hip/hip_runtime.h>
#include <math.h>

#define DD 1024
#define TT 4096
#define BB 16
#define KK 4
#define CC 1000
#define TEMP_F 0.07f
#define EPS_F 1e-6f
#define NPROJ 2048
#define SWEEP (NPROJ * 4)                 // 8192 tokens per sweep
#define ITERS ((BB * TT) / SWEEP)         // 8

// ---------- sorted-8 register-list helpers (all static indexing) ----------
#define CE(a, b) { float _mx = fmaxf(a, b), _mn = fminf(a, b); a = _mx; b = _mn; }
#define INS8(y_) { float y = (y_); \
    CE(s0, y) CE(s1, y) CE(s2, y) CE(s3, y) CE(s4, y) CE(s5, y) CE(s6, y) CE(s7, y) }
#define RESORT8() { \
    CE(s0, s4) CE(s1, s5) CE(s2, s6) CE(s3, s7) \
    CE(s0, s2) CE(s1, s3) CE(s4, s6) CE(s5, s7) \
    CE(s0, s1) CE(s2, s3) CE(s4, s5) CE(s6, s7) }
#define WMERGE(off) { \
    float t0 = __shfl_xor(s0, off), t1 = __shfl_xor(s1, off), \
          t2 = __shfl_xor(s2, off), t3 = __shfl_xor(s3, off), \
          t4 = __shfl_xor(s4, off), t5 = __shfl_xor(s5, off), \
          t6 = __shfl_xor(s6, off), t7 = __shfl_xor(s7, off); \
    s0 = fmaxf(s0, t7); s1 = fmaxf(s1, t6); s2 = fmaxf(s2, t5); s3 = fmaxf(s3, t4); \
    s4 = fmaxf(s4, t3); s5 = fmaxf(s5, t2); s6 = fmaxf(s6, t1); s7 = fmaxf(s7, t0); \
    RESORT8() }

// Kernel 1 (1 block): u_k = normalize(v_k*sigmoid(m_k)) (wave w = k), then
// G[6] = {u0.u1, u0.u2, u0.u3, u1.u2, u1.u3, u2.u3} distributed over waves.
__global__ __launch_bounds__(256) void k_u_g(const float* __restrict__ v,
                                             const float* __restrict__ m,
                                             float* __restrict__ u_ws,
                                             float* __restrict__ G_ws) {
    __shared__ float u_lds[KK * DD];
    int tid = threadIdx.x, w = tid >> 6, lane = tid & 63;
    float s_reg[16];
    float ss = 0.f;
#pragma unroll
    for (int i = 0; i < 16; ++i) {
        int d = lane + i * 64;
        float mv = m[w * DD + d];
        float s = v[w * DD + d] * (1.f / (1.f + expf(-mv)));
        s_reg[i] = s; ss += s * s;
    }
#pragma unroll
    for (int off = 32; off; off >>= 1) ss += __shfl_xor(ss, off);
    float inv = 1.f / (sqrtf(ss) + EPS_F);
#pragma unroll
    for (int i = 0; i < 16; ++i) {
        int d = lane + i * 64;
        float uu = s_reg[i] * inv;
        u_lds[w * DD + d] = uu;
        u_ws[w * DD + d] = uu;
    }
    __syncthreads();
    for (int p = w; p < 6; p += 4) {
        int j = (p < 3) ? 0 : ((p < 5) ? 1 : 2);
        int k = (p < 3) ? (p + 1) : ((p < 5) ? (p - 1) : 3);
        float acc = 0.f;
#pragma unroll
        for (int i = 0; i < 16; ++i) {
            int d = lane + i * 64;
            acc += u_lds[j * DD + d] * u_lds[k * DD + d];
        }
#pragma unroll
        for (int off = 32; off; off >>= 1) acc += __shfl_xor(acc, off);
        if (lane == 0) G_ws[p] = acc;
    }
}

// Kernel 2: blocks [0,NPROJ): c0[b,t,k] = E[b,t,:].u_k  (U in VGPRs, zero
// preamble compute, next-iter loads prefetched past the shuffle chain)
//           blocks [NPROJ,NPROJ+CC): wdot[k][c] = cls_W[k,c,:].u_k
__global__ __launch_bounds__(256) void k_proj_wu(const float* __restrict__ E,
                                                 const float* __restrict__ W,
                                                 const float* __restrict__ u_ws,
                                                 float* __restrict__ c0,
                                                 float* __restrict__ wdot) {
    int tid = threadIdx.x, w = tid >> 6, lane = tid & 63;
    if (blockIdx.x < NPROJ) {
        float4 U[KK][4];
#pragma unroll
        for (int k = 0; k < KK; ++k)
#pragma unroll
            for (int j = 0; j < 4; ++j)
                U[k][j] = *reinterpret_cast<const float4*>(u_ws + k * DD + lane * 4 + j * 256);
        size_t base = (size_t)(blockIdx.x * 4 + w);
        const float* e0 = E + base * DD + lane * 4;
        float4 ev[4];
#pragma unroll
        for (int j = 0; j < 4; ++j)
            ev[j] = *reinterpret_cast<const float4*>(e0 + j * 256);
#pragma unroll 1
        for (int it = 0; it < ITERS - 1; ++it) {
            // prefetch next token's 64B before the dependent compute phase
            const float* en = e0 + (size_t)(it + 1) * ((size_t)SWEEP * DD);
            float4 evn[4];
#pragma unroll
            for (int j = 0; j < 4; ++j)
                evn[j] = *reinterpret_cast<const float4*>(en + j * 256);
            float a0 = 0.f, a1 = 0.f, a2 = 0.f, a3 = 0.f;
#pragma unroll
            for (int j = 0; j < 4; ++j) {
                a0 += ev[j].x * U[0][j].x + ev[j].y * U[0][j].y + ev[j].z * U[0][j].z + ev[j].w * U[0][j].w;
                a1 += ev[j].x * U[1][j].x + ev[j].y * U[1][j].y + ev[j].z * U[1][j].z + ev[j].w * U[1][j].w;
                a2 += ev[j].x * U[2][j].x + ev[j].y * U[2][j].y + ev[j].z * U[2][j].z + ev[j].w * U[2][j].w;
                a3 += ev[j].x * U[3][j].x + ev[j].y * U[3][j].y + ev[j].z * U[3][j].z + ev[j].w * U[3][j].w;
            }
#pragma unroll
            for (int off = 32; off; off >>= 1) {
                a0 += __shfl_xor(a0, off);
                a1 += __shfl_xor(a1, off);
                a2 += __shfl_xor(a2, off);
                a3 += __shfl_xor(a3, off);
            }
            if (lane == 0)
                *reinterpret_cast<float4*>(c0 + (base + (size_t)it * SWEEP) * 4) =
                    make_float4(a0, a1, a2, a3);
#pragma unroll
            for (int j = 0; j < 4; ++j) ev[j] = evn[j];
        }
        {   // final iteration (no prefetch)
            float a0 = 0.f, a1 = 0.f, a2 = 0.f, a3 = 0.f;
#pragma unroll
            for (int j = 0; j < 4; ++j) {
                a0 += ev[j].x * U[0][j].x + ev[j].y * U[0][j].y + ev[j].z * U[0][j].z + ev[j].w * U[0][j].w;
                a1 += ev[j].x * U[1][j].x + ev[j].y * U[1][j].y + ev[j].z * U[1][j].z + ev[j].w * U[1][j].w;
                a2 += ev[j].x * U[2][j].x + ev[j].y * U[2][j].y + ev[j].z * U[2][j].z + ev[j].w * U[2][j].w;
                a3 += ev[j].x * U[3][j].x + ev[j].y * U[3][j].y + ev[j].z * U[3][j].z + ev[j].w * U[3][j].w;
            }
#pragma unroll
            for (int off = 32; off; off >>= 1) {
                a0 += __shfl_xor(a0, off);
                a1 += __shfl_xor(a1, off);
                a2 += __shfl_xor(a2, off);
                a3 += __shfl_xor(a3, off);
            }
            if (lane == 0)
                *reinterpret_cast<float4*>(c0 + (base + (size_t)(ITERS - 1) * SWEEP) * 4) =
                    make_float4(a0, a1, a2, a3);
        }
    } else {
        int c = blockIdx.x - NPROJ;  // wave w handles k=w
        const float* wr = W + ((size_t)w * CC + c) * DD;
        const float* ur = u_ws + w * DD;
        float acc = 0.f;
#pragma unroll
        for (int j = 0; j < 4; ++j) {
            float4 wv = *reinterpret_cast<const float4*>(wr + lane * 4 + j * 256);
            float4 uv = *reinterpret_cast<const float4*>(ur + lane * 4 + j * 256);
            acc += wv.x * uv.x + wv.y * uv.y + wv.z * uv.z + wv.w * uv.w;
        }
#pragma unroll
        for (int off = 32; off; off >>= 1) acc += __shfl_xor(acc, off);
        if (lane == 0) wdot[w * CC + c] = acc;
    }
}

// Kernel 3: one block per b; wave w owns k=w (peel recurrence + softmax stats +
// single-pass top-8, wave-local), then the block writes out[b,:].
__global__ __launch_bounds__(256) void k_peel_out(const float* __restrict__ c0,
                                                  const float* __restrict__ G_ws,
                                                  const float* __restrict__ beta,
                                                  const float* __restrict__ wdot,
                                                  const float* __restrict__ bias,
                                                  const float* __restrict__ alpha,
                                                  float* __restrict__ out) {
    __shared__ float csc[KK];
    int tid = threadIdx.x, w = tid >> 6, lane = tid & 63;
    int b = blockIdx.x;
    float g01 = G_ws[0], g02 = G_ws[1], g03 = G_ws[2];
    float g12 = G_ws[3], g13 = G_ws[4], g23 = G_ws[5];
    float b0 = beta[0], b1 = beta[1], b2 = beta[2];
    float fk[64];
    float mx = -INFINITY;
#pragma unroll
    for (int i = 0; i < 64; ++i) {
        int t = lane + i * 64;
        float4 cv = *reinterpret_cast<const float4*>(c0 + ((size_t)b * TT + t) * 4);
        float f0 = cv.x;
        float f1 = cv.y - b0 * g01 * f0;
        float f2 = cv.z - b0 * g02 * f0 - b1 * g12 * f1;
        float f3 = cv.w - b0 * g03 * f0 - b1 * g13 * f1 - b2 * g23 * f2;
        float f = (w == 0) ? f0 : ((w == 1) ? f1 : ((w == 2) ? f2 : f3));
        fk[i] = f; mx = fmaxf(mx, f);
    }
#pragma unroll
    for (int off = 32; off; off >>= 1) mx = fmaxf(mx, __shfl_xor(mx, off));
    const float invT = 1.f / TEMP_F;
    float se = 0.f, sce = 0.f;
#pragma unroll
    for (int i = 0; i < 64; ++i) {
        float e = expf((fk[i] - mx) * invT);
        se += e; sce += fk[i] * e;
    }
#pragma unroll
    for (int off = 32; off; off >>= 1) {
        se += __shfl_xor(se, off);
        sce += __shfl_xor(sce, off);
    }
    float zsoft = sce / se;
    float s0 = -INFINITY, s1 = -INFINITY, s2 = -INFINITY, s3 = -INFINITY,
          s4 = -INFINITY, s5 = -INFINITY, s6 = -INFINITY, s7 = -INFINITY;
#pragma unroll
    for (int i = 0; i < 64; ++i) INS8(fk[i]);
    WMERGE(1) WMERGE(2) WMERGE(4) WMERGE(8) WMERGE(16) WMERGE(32)
    if (lane == 0) {
        float sumtop = s0 + s1 + s2 + s3 + s4 + s5 + s6 + s7;
        csc[w] = 0.5f * (sumtop + zsoft);
    }
    __syncthreads();
    float al0 = alpha[0], al1 = alpha[1], al2 = alpha[2], al3 = alpha[3];
    float c0s = csc[0], c1s = csc[1], c2s = csc[2], c3s = csc[3];
    for (int c = tid; c < CC; c += 256) {
        float s = al0 * (c0s * wdot[0 * CC + c] + bias[0 * CC + c])
                + al1 * (c1s * wdot[1 * CC + c] + bias[1 * CC + c])
                + al2 * (c2s * wdot[2 * CC + c] + bias[2 * CC + c])
                + al3 * (c3s * wdot[3 * CC + c] + bias[3 * CC + c]);
        out[(size_t)b * CC + c] = s;
    }
}

extern "C" void kernel_launch(void* const* d_in, const int* in_sizes, int n_in,
                              void* d_out, int out_size, void* d_ws, size_t ws_size,
                              hipStream_t stream) {
    const float* E     = (const float*)d_in[0];
    const float* v     = (const float*)d_in[1];
    const float* m     = (const float*)d_in[2];
    const float* W     = (const float*)d_in[3];
    const float* cb    = (const float*)d_in[4];
    const float* beta  = (const float*)d_in[5];
    const float* alpha = (const float*)d_in[6];
    float* out = (float*)d_out;
    float* ws = (float*)d_ws;

    float* u_ws = ws;           // K*D = 4096 floats
    float* G_ws = ws + 4096;    // 6 floats (pad to 16)
    float* wdot = ws + 4112;    // K*C = 4000 floats (pad to 4080 -> next 16B)
    float* c0   = ws + 8192;    // B*T*K = 262144 floats, 16B-aligned

    k_u_g<<<1, 256, 0, stream>>>(v, m, u_ws, G_ws);
    k_proj_wu<<<NPROJ + CC, 256, 0, stream>>>(E, W, u_ws, c0, wdot);
    k_peel_out<<<BB, 256, 0, stream>>>(c0, G_ws, beta, wdot, cb, alpha, out);
}